// Round 1
// baseline (840.992 us; speedup 1.0000x reference)
//
#include <hip/hip_runtime.h>
#include <stdint.h>

typedef unsigned short u16;
typedef __attribute__((ext_vector_type(8))) short bf16x8;
typedef __attribute__((ext_vector_type(4))) float floatx4;
typedef __attribute__((ext_vector_type(4))) u16 u16x4;
typedef __attribute__((ext_vector_type(8))) u16 u16x8;

constexpr int B_ = 4, E_ = 16, N_ = 1024, D_ = 512;
constexpr int BE = B_ * E_;

__device__ __forceinline__ u16 f2bf(float f) {
    union { float f; uint32_t u; } v; v.f = f;
    return (u16)((v.u + 0x7fffu + ((v.u >> 16) & 1u)) >> 16);
}
__device__ __forceinline__ float bf2f(u16 h) {
    union { uint32_t u; float f; } v; v.u = ((uint32_t)h) << 16;
    return v.f;
}

// async global->LDS, 16B per lane, LDS dest = wave-uniform base + lane*16
#define GLDS(g, l) __builtin_amdgcn_global_load_lds( \
    (const __attribute__((address_space(1))) void*)(g), \
    (__attribute__((address_space(3))) void*)(l), 16, 0, 0)

// ---------------------------------------------------------------------------
// Transpose + split-convert: in [z][R][C] fp32 -> outH/outL [z][C][R] bf16
// grid = (C/32, R/32, z), block = 256
// ---------------------------------------------------------------------------
__global__ __launch_bounds__(256)
void transpose_split(const float* __restrict__ in, u16* __restrict__ outH,
                     u16* __restrict__ outL, int R, int C)
{
    __shared__ float t[32][33];
    const int z = blockIdx.z;
    const float* ib = in + (size_t)z * R * C;
    u16* oh = outH + (size_t)z * R * C;
    u16* ol = outL + (size_t)z * R * C;
    const int r0 = blockIdx.y * 32, c0 = blockIdx.x * 32;
    const int t8 = threadIdx.x & 7, td = threadIdx.x >> 3;

    float4 v = *(const float4*)&ib[(size_t)(r0 + td) * C + c0 + t8 * 4];
    t[td][t8 * 4 + 0] = v.x;
    t[td][t8 * 4 + 1] = v.y;
    t[td][t8 * 4 + 2] = v.z;
    t[td][t8 * 4 + 3] = v.w;
    __syncthreads();

    u16x4 ph, pl;
    float w0 = t[t8 * 4 + 0][td], w1 = t[t8 * 4 + 1][td];
    float w2 = t[t8 * 4 + 2][td], w3 = t[t8 * 4 + 3][td];
    ph.x = f2bf(w0); pl.x = f2bf(w0 - bf2f(ph.x));
    ph.y = f2bf(w1); pl.y = f2bf(w1 - bf2f(ph.y));
    ph.z = f2bf(w2); pl.z = f2bf(w2 - bf2f(ph.z));
    ph.w = f2bf(w3); pl.w = f2bf(w3 - bf2f(ph.w));
    const size_t o = (size_t)(c0 + td) * R + r0 + t8 * 4;
    *(u16x4*)&oh[o] = ph;
    *(u16x4*)&ol[o] = pl;
}

// Both weight transposes (w2 and w1) in ONE dispatch. R=C=512, z in [0,2E)
__global__ __launch_bounds__(256)
void transpose_split_w(const float* __restrict__ inA, u16* __restrict__ oAh, u16* __restrict__ oAl,
                       const float* __restrict__ inB, u16* __restrict__ oBh, u16* __restrict__ oBl)
{
    __shared__ float t[32][33];
    int z = blockIdx.z;
    const float* in; u16* oh; u16* ol;
    if (z < E_) { in = inA; oh = oAh; ol = oAl; }
    else        { z -= E_; in = inB; oh = oBh; ol = oBl; }
    const int R = 512, C = 512;
    const float* ib = in + (size_t)z * R * C;
    u16* ohz = oh + (size_t)z * R * C;
    u16* olz = ol + (size_t)z * R * C;
    const int r0 = blockIdx.y * 32, c0 = blockIdx.x * 32;
    const int t8 = threadIdx.x & 7, td = threadIdx.x >> 3;

    float4 v = *(const float4*)&ib[(size_t)(r0 + td) * C + c0 + t8 * 4];
    t[td][t8 * 4 + 0] = v.x;
    t[td][t8 * 4 + 1] = v.y;
    t[td][t8 * 4 + 2] = v.z;
    t[td][t8 * 4 + 3] = v.w;
    __syncthreads();

    u16x4 ph, pl;
    float w0 = t[t8 * 4 + 0][td], w1 = t[t8 * 4 + 1][td];
    float w2 = t[t8 * 4 + 2][td], w3 = t[t8 * 4 + 3][td];
    ph.x = f2bf(w0); pl.x = f2bf(w0 - bf2f(ph.x));
    ph.y = f2bf(w1); pl.y = f2bf(w1 - bf2f(ph.y));
    ph.z = f2bf(w2); pl.z = f2bf(w2 - bf2f(ph.z));
    ph.w = f2bf(w3); pl.w = f2bf(w3 - bf2f(ph.w));
    const size_t o = (size_t)(c0 + td) * R + r0 + t8 * 4;
    *(u16x4*)&ohz[o] = ph;
    *(u16x4*)&olz[o] = pl;
}

// ---------------------------------------------------------------------------
// Split-bf16 GEMM (3 MFMA: hh + hl + lh): C[z][m][n] = sum_k A[m][k]*B[n][k]
// 128x128 tile, 256 threads (4 waves), BK=32, 16x16x32 bf16 MFMA.
//
// LDS layout = FRAGMENT ORDER (conflict-free): 16-B chunk id ci = grp*64 + ln,
//   grp = half*8 + i*2 + lo   (half = row-half 0/1, i = 16-row subtile, lo = hi/lo part)
//   chunk data = A[row = half*64 + i*16 + (ln&15)][k = (ln>>4)*8 .. +8]  (hi or lo)
// => every MFMA fragment read is ds_read_b128 at base + ln*16 (contiguous 1 KiB).
// GLDS staging: wave wv stages grps 4wv..4wv+3 of both A and B (8 GLDS/step);
// global source address carries the permutation (per-lane), LDS dest is linear.
//
// sym=1: A==B symmetric output (G = X^T X). grid.x = 10 upper-tri blocks,
// epilogue mirrors off-diagonal tiles (exactly equal values; write bytes unchanged).
// ---------------------------------------------------------------------------
__global__ __launch_bounds__(256)
void gemm_split3(const u16* __restrict__ Ah, const u16* __restrict__ Al,
                 int aMod, long aStride,
                 const u16* __restrict__ Bh, const u16* __restrict__ Bl,
                 int bMod, long bStride,
                 u16* __restrict__ Ch, u16* __restrict__ Cl,
                 float* __restrict__ Cf,
                 int M, int N, int K, int f32out, int sym)
{
    const int z = blockIdx.z;
    const long za = aMod ? (z % aMod) : z;
    const long zb = bMod ? (z % bMod) : z;
    const u16* pAh = Ah + za * aStride;
    const u16* pAl = Al + za * aStride;
    const u16* pBh = Bh + zb * bStride;
    const u16* pBl = Bl + zb * bStride;

    __shared__ __attribute__((aligned(16))) u16 sA[8192];   // 16 KiB, 16 grps
    __shared__ __attribute__((aligned(16))) u16 sB[8192];

    const int tid = threadIdx.x;
    const int wv = tid >> 6, ln = tid & 63;
    const int lq = ln >> 4, lm = ln & 15;

    int bi, bj;
    if (sym) {
        const int idx = blockIdx.x;          // upper triangle of 4x4
        bi = (idx < 4) ? 0 : (idx < 7) ? 1 : (idx < 9) ? 2 : 3;
        bj = idx - ((bi == 0) ? 0 : (bi == 1) ? 3 : (bi == 2) ? 5 : 6);
    } else { bi = blockIdx.x; bj = blockIdx.y; }
    const int m0 = bi * 128, n0 = bj * 128;

    // per-lane staging sources (hi/lo select is wave-uniform: grp bit 0)
    const u16* srcA[4];
    const u16* srcB[4];
#pragma unroll
    for (int g = 0; g < 4; ++g) {
        const int grp = wv * 4 + g;
        const int row = (grp >> 3) * 64 + ((grp >> 1) & 3) * 16 + lm;
        srcA[g] = ((grp & 1) ? pAl : pAh) + (long)(m0 + row) * K + lq * 8;
        srcB[g] = ((grp & 1) ? pBl : pBh) + (long)(n0 + row) * K + lq * 8;
    }

    const int wm = wv >> 1, wn = wv & 1;

    floatx4 acc[4][4];
#pragma unroll
    for (int i = 0; i < 4; ++i)
#pragma unroll
        for (int j = 0; j < 4; ++j) acc[i][j] = (floatx4){0.f, 0.f, 0.f, 0.f};

    for (int k0 = 0; k0 < K; k0 += 32) {
#pragma unroll
        for (int g = 0; g < 4; ++g) {
            GLDS(srcA[g] + k0, sA + (wv * 4 + g) * 512);
            GLDS(srcB[g] + k0, sB + (wv * 4 + g) * 512);
        }
        __syncthreads();

        bf16x8 ah[4], al[4], bh[4], bl[4];
#pragma unroll
        for (int i = 0; i < 4; ++i) {
            const int ga = (wm * 8 + i * 2) * 512 + ln * 8;
            ah[i] = *(const bf16x8*)&sA[ga];
            al[i] = *(const bf16x8*)&sA[ga + 512];
        }
#pragma unroll
        for (int j = 0; j < 4; ++j) {
            const int gb = (wn * 8 + j * 2) * 512 + ln * 8;
            bh[j] = *(const bf16x8*)&sB[gb];
            bl[j] = *(const bf16x8*)&sB[gb + 512];
        }
#pragma unroll
        for (int i = 0; i < 4; ++i)
#pragma unroll
            for (int j = 0; j < 4; ++j) {
                acc[i][j] = __builtin_amdgcn_mfma_f32_16x16x32_bf16(ah[i], bh[j], acc[i][j], 0, 0, 0);
                acc[i][j] = __builtin_amdgcn_mfma_f32_16x16x32_bf16(ah[i], bl[j], acc[i][j], 0, 0, 0);
                acc[i][j] = __builtin_amdgcn_mfma_f32_16x16x32_bf16(al[i], bh[j], acc[i][j], 0, 0, 0);
            }
        __syncthreads();
    }

    // epilogue: C/D layout col=lane&15, row=quad*4+reg
    const long cbase = (long)z * M * N;
#pragma unroll
    for (int i = 0; i < 4; ++i)
#pragma unroll
        for (int j = 0; j < 4; ++j) {
            const int col = n0 + wn * 64 + j * 16 + lm;
#pragma unroll
            for (int r = 0; r < 4; ++r) {
                const int row = m0 + wm * 64 + i * 16 + lq * 4 + r;
                const float v = acc[i][j][r];
                if (f32out) {
                    Cf[cbase + (long)row * N + col] = v;
                } else {
                    const u16 h = f2bf(v);
                    const u16 l = f2bf(v - bf2f(h));
                    Ch[cbase + (long)row * N + col] = h;
                    Cl[cbase + (long)row * N + col] = l;
                    if (sym && bi != bj) {          // mirror: exact same values
                        Ch[cbase + (long)col * N + row] = h;
                        Cl[cbase + (long)col * N + row] = l;
                    }
                }
            }
        }
}

// ---------------------------------------------------------------------------
// Plain bf16 GEMM, one operand staged on-the-fly from fp32 (hi only).
// OTFA=1: A = Qf (fp32 otf), B = Pb (bf16). OTFA=0: A = Pb, B = Qf.
// Same fragment-order LDS layout (8 grps per operand, 8 KiB each):
//   grp = half*4 + i ; chunk data = Op[row = (grp>>2)*64 + (grp&3)*16 + (ln&15)]
//                                  [k = (ln>>4)*8 .. +8]
// bf16 side staged by GLDS (2/wave); fp32 side: each thread converts 2 chunks
// (2x float4 -> bf16x8) and ds_write_b128's them - all LDS traffic contiguous.
// ---------------------------------------------------------------------------
template<int OTFA, int F32OUT>
__global__ __launch_bounds__(256)
void gemm_plain(const float* __restrict__ Qf, int qMod, long qStride,
                const u16* __restrict__ Pb, int pMod, long pStride,
                u16* __restrict__ Cb, float* __restrict__ Cf,
                int M, int N, int K)
{
    const int z = blockIdx.z;
    const float* pQ = Qf + (long)(qMod ? z % qMod : z) * qStride;
    const u16*  pP = Pb + (long)(pMod ? z % pMod : z) * pStride;

    __shared__ __attribute__((aligned(16))) u16 sA[4096];   // 8 KiB, 8 grps
    __shared__ __attribute__((aligned(16))) u16 sB[4096];

    const int tid = threadIdx.x;
    const int wv = tid >> 6, ln = tid & 63;
    const int lq = ln >> 4, lm = ln & 15;
    const int m0 = blockIdx.x * 128, n0 = blockIdx.y * 128;

    u16* sBF = OTFA ? sB : sA;   // bf16-side (GLDS) LDS tile
    u16* sQ  = OTFA ? sA : sB;   // otf-fp32-side LDS tile
    const int bfRow0 = OTFA ? n0 : m0;
    const int qRow0  = OTFA ? m0 : n0;

    // GLDS bf16 sources: 2 grps per wave
    const u16* srcP[2];
#pragma unroll
    for (int g = 0; g < 2; ++g) {
        const int grp = wv * 2 + g;
        const int row = (grp >> 2) * 64 + (grp & 3) * 16 + lm;
        srcP[g] = pP + (long)(bfRow0 + row) * K + lq * 8;
    }

    // otf fp32: thread stages chunks {tid, tid+256}
    int orow[2], ok[2];
#pragma unroll
    for (int s = 0; s < 2; ++s) {
        const int ci = tid + s * 256;
        const int grp = ci >> 6, l = ci & 63;
        orow[s] = qRow0 + (grp >> 2) * 64 + (grp & 3) * 16 + (l & 15);
        ok[s]   = (l >> 4) * 8;
    }

    const int wm = wv >> 1, wn = wv & 1;

    floatx4 acc[4][4];
#pragma unroll
    for (int i = 0; i < 4; ++i)
#pragma unroll
        for (int j = 0; j < 4; ++j) acc[i][j] = (floatx4){0.f, 0.f, 0.f, 0.f};

    for (int k0 = 0; k0 < K; k0 += 32) {
#pragma unroll
        for (int g = 0; g < 2; ++g)
            GLDS(srcP[g] + k0, sBF + (wv * 2 + g) * 512);
#pragma unroll
        for (int s = 0; s < 2; ++s) {
            const float* src = &pQ[(long)orow[s] * K + k0 + ok[s]];
            const float4 v0 = *(const float4*)src;
            const float4 v1 = *(const float4*)(src + 4);
            u16x8 pk;
            pk[0] = f2bf(v0.x); pk[1] = f2bf(v0.y); pk[2] = f2bf(v0.z); pk[3] = f2bf(v0.w);
            pk[4] = f2bf(v1.x); pk[5] = f2bf(v1.y); pk[6] = f2bf(v1.z); pk[7] = f2bf(v1.w);
            *(u16x8*)&sQ[(tid + s * 256) * 8] = pk;
        }
        __syncthreads();

        bf16x8 af[4], bg[4];
#pragma unroll
        for (int i = 0; i < 4; ++i)
            af[i] = *(const bf16x8*)&sA[(wm * 4 + i) * 512 + ln * 8];
#pragma unroll
        for (int j = 0; j < 4; ++j)
            bg[j] = *(const bf16x8*)&sB[(wn * 4 + j) * 512 + ln * 8];
#pragma unroll
        for (int i = 0; i < 4; ++i)
#pragma unroll
            for (int j = 0; j < 4; ++j)
                acc[i][j] = __builtin_amdgcn_mfma_f32_16x16x32_bf16(af[i], bg[j], acc[i][j], 0, 0, 0);
        __syncthreads();
    }

    const long cbase = (long)z * M * N;
#pragma unroll
    for (int i = 0; i < 4; ++i)
#pragma unroll
        for (int j = 0; j < 4; ++j) {
            const int col = n0 + wn * 64 + j * 16 + lm;
#pragma unroll
            for (int r = 0; r < 4; ++r) {
                const int row = m0 + wm * 64 + i * 16 + lq * 4 + r;
                const long idx = cbase + (long)row * N + col;
                if (F32OUT) Cf[idx] = acc[i][j][r];
                else        Cb[idx] = f2bf(acc[i][j][r]);
            }
        }
}

// ---------------------------------------------------------------------------
// Column softmax: AT fp32 [z][512][512], normalize over row index c per col g.
// ---------------------------------------------------------------------------
__global__ __launch_bounds__(128)
void softmax_col(const float* __restrict__ AT, u16* __restrict__ PT)
{
    const int z = blockIdx.x >> 2, gq = blockIdx.x & 3;
    const long base = (long)z * 512 * 512 + gq * 128 + threadIdx.x;
    const float* a = AT + base;
    u16* p = PT + base;

    float m = -1e30f, l = 0.f;
    for (int c = 0; c < 512; ++c) {
        const float v = a[(long)c * 512];
        const float mn = fmaxf(m, v);
        l = l * __expf(m - mn) + __expf(v - mn);
        m = mn;
    }
    const float inv = 1.0f / l;
    for (int c = 0; c < 512; ++c) {
        const float v = a[(long)c * 512];
        p[(long)c * 512] = f2bf(__expf(v - m) * inv);
    }
}

// ---------------------------------------------------------------------------
// Orchestration.  atten = softmax(W1^T (X^T X) W2), out = X (W3 atten).
// Buffer schedule (ws 64 MiB + d_out 128 MiB scratch):
//   C1: X -> XhT(O[0:64)), XlT(O[64:128))
//   S1: Gh(ws[0:32)), Gl(ws[32:64)) = XT*XT^T   (K=1024, SYMMETRIC: 10 blocks/z)
//   C2: w2 -> W2T h/l (O[64:80)), w1 -> W1T h/l (O[80:96))   [XlT dead]
//   S2: Uh(O[0:32)), Ul(O[32:64)) = W2T*G^T                  [XhT dead]
//   S3: AT fp32 (ws[0:64)) = U*W1T^T                         [G dead]
//   S4: PT bf16 (O[64:96)) = colsoftmax(AT)                  [W2T/W1T dead]
//   S5: MT bf16 (ws[0:32)) = PT*W3^T (W3 otf)                [AT dead]
//   S6: out fp32 (d_out) = X*MT^T (X otf)   [reads only x, MT]
// ---------------------------------------------------------------------------
extern "C" void kernel_launch(void* const* d_in, const int* in_sizes, int n_in,
                              void* d_out, int out_size, void* d_ws, size_t ws_size,
                              hipStream_t stream)
{
    const float* x  = (const float*)d_in[0];
    const float* w1 = (const float*)d_in[1];
    const float* w2 = (const float*)d_in[2];
    const float* w3 = (const float*)d_in[3];

    char* O = (char*)d_out;
    char* W = (char*)d_ws;
    const size_t MB = 1ull << 20;

    u16* XhT  = (u16*)O;
    u16* XlT  = (u16*)(O + 64 * MB);
    u16* Gh   = (u16*)W;
    u16* Gl   = (u16*)(W + 32 * MB);
    u16* W2Th = (u16*)(O + 64 * MB);
    u16* W2Tl = (u16*)(O + 72 * MB);
    u16* W1Th = (u16*)(O + 80 * MB);
    u16* W1Tl = (u16*)(O + 88 * MB);
    u16* Uh   = (u16*)O;
    u16* Ul   = (u16*)(O + 32 * MB);
    float* AT = (float*)W;
    u16* PT   = (u16*)(O + 64 * MB);
    u16* MT   = (u16*)W;
    float* out = (float*)d_out;

    const long sXT = (long)512 * 1024;
    const long sSq = (long)512 * 512;

    // C1: X [z][1024][512] -> XhT/XlT [z][512][1024]
    transpose_split<<<dim3(16, 32, BE), 256, 0, stream>>>(x, XhT, XlT, 1024, 512);
    // S1: G = XT * XT^T (split3, K=1024, symmetric: upper-tri + mirror)
    gemm_split3<<<dim3(10, 1, BE), 256, 0, stream>>>(
        XhT, XlT, 0, sXT, XhT, XlT, 0, sXT,
        Gh, Gl, nullptr, 512, 512, 1024, 0, 1);
    // C2: w2 -> W2T, w1 -> W1T (one dispatch)
    transpose_split_w<<<dim3(16, 16, 2 * E_), 256, 0, stream>>>(
        w2, W2Th, W2Tl, w1, W1Th, W1Tl);
    // S2: U = W2T * G^T  (G symmetric)
    gemm_split3<<<dim3(4, 4, BE), 256, 0, stream>>>(
        W2Th, W2Tl, E_, sSq, Gh, Gl, 0, sSq,
        Uh, Ul, nullptr, 512, 512, 512, 0, 0);
    // S3: AT = U * W1T^T  -> fp32 logits, transposed ([c][g])
    gemm_split3<<<dim3(4, 4, BE), 256, 0, stream>>>(
        Uh, Ul, 0, sSq, W1Th, W1Tl, E_, sSq,
        nullptr, nullptr, AT, 512, 512, 512, 1, 0);
    // S4: softmax over c (down the columns of AT)
    softmax_col<<<dim3(BE * 4), 128, 0, stream>>>(AT, PT);
    // S5: MT = PT * W3^T  (W3 fp32 on-the-fly as B)
    gemm_plain<0, 0><<<dim3(4, 4, BE), 256, 0, stream>>>(
        w3, E_, sSq, PT, 0, sSq, MT, nullptr, 512, 512, 512);
    // S6: out = X * MT^T  (X fp32 on-the-fly as A)
    gemm_plain<1, 1><<<dim3(8, 4, BE), 256, 0, stream>>>(
        x, 0, (long)N_ * D_, MT, 0, sSq, nullptr, out, 1024, 512, 512);
}

// Round 2
// 750.834 us; speedup vs baseline: 1.1201x; 1.1201x over previous
//
#include <hip/hip_runtime.h>
#include <stdint.h>

typedef unsigned short u16;
typedef __attribute__((ext_vector_type(8))) short bf16x8;
typedef __attribute__((ext_vector_type(4))) float floatx4;
typedef __attribute__((ext_vector_type(4))) u16 u16x4;
typedef __attribute__((ext_vector_type(8))) u16 u16x8;

constexpr int B_ = 4, E_ = 16, N_ = 1024, D_ = 512;
constexpr int BE = B_ * E_;

__device__ __forceinline__ u16 f2bf(float f) {
    union { float f; uint32_t u; } v; v.f = f;
    return (u16)((v.u + 0x7fffu + ((v.u >> 16) & 1u)) >> 16);
}
__device__ __forceinline__ float bf2f(u16 h) {
    union { uint32_t u; float f; } v; v.u = ((uint32_t)h) << 16;
    return v.f;
}

// async global->LDS, 16B per lane, LDS dest = wave-uniform base + lane*16
#define GLDS(g, l) __builtin_amdgcn_global_load_lds( \
    (const __attribute__((address_space(1))) void*)(g), \
    (__attribute__((address_space(3))) void*)(l), 16, 0, 0)

// ---------------------------------------------------------------------------
// K-quad rotation layout ("rotated fragment order"):
// A BK=32 panel of 16 rows is one LDS "grp" = 64 chunks x 16B = 1KB.
// Chunk ci (staged by lane ci): global row rg = ci>>2, k-quad kq = ((ci&3)+(rg>>1))&3.
//  - staging: 4 consecutive lanes cover ONE contiguous 64B row segment (VMEM
//    coalescing identical to plain row-major; only intra-line lane order rotated).
//  - fragment read: lane (lm,lq) reads chunk 4*lm + ((lq-(lm>>1))&3); the 16B-group
//    sequence (4t-(t>>1)) mod 8 is a permutation of 0..7 for every 8 consecutive
//    lanes -> conflict-free ds_read_b128.
// ---------------------------------------------------------------------------

// ---------------------------------------------------------------------------
// Transpose + split-convert: in [z][R][C] fp32 -> outH/outL [z][C][R] bf16
// ---------------------------------------------------------------------------
__global__ __launch_bounds__(256)
void transpose_split(const float* __restrict__ in, u16* __restrict__ outH,
                     u16* __restrict__ outL, int R, int C)
{
    __shared__ float t[32][33];
    const int z = blockIdx.z;
    const float* ib = in + (size_t)z * R * C;
    u16* oh = outH + (size_t)z * R * C;
    u16* ol = outL + (size_t)z * R * C;
    const int r0 = blockIdx.y * 32, c0 = blockIdx.x * 32;
    const int t8 = threadIdx.x & 7, td = threadIdx.x >> 3;

    float4 v = *(const float4*)&ib[(size_t)(r0 + td) * C + c0 + t8 * 4];
    t[td][t8 * 4 + 0] = v.x;
    t[td][t8 * 4 + 1] = v.y;
    t[td][t8 * 4 + 2] = v.z;
    t[td][t8 * 4 + 3] = v.w;
    __syncthreads();

    u16x4 ph, pl;
    float w0 = t[t8 * 4 + 0][td], w1 = t[t8 * 4 + 1][td];
    float w2 = t[t8 * 4 + 2][td], w3 = t[t8 * 4 + 3][td];
    ph.x = f2bf(w0); pl.x = f2bf(w0 - bf2f(ph.x));
    ph.y = f2bf(w1); pl.y = f2bf(w1 - bf2f(ph.y));
    ph.z = f2bf(w2); pl.z = f2bf(w2 - bf2f(ph.z));
    ph.w = f2bf(w3); pl.w = f2bf(w3 - bf2f(ph.w));
    const size_t o = (size_t)(c0 + td) * R + r0 + t8 * 4;
    *(u16x4*)&oh[o] = ph;
    *(u16x4*)&ol[o] = pl;
}

// Both weight transposes (w2 and w1) in ONE dispatch. R=C=512, z in [0,2E)
__global__ __launch_bounds__(256)
void transpose_split_w(const float* __restrict__ inA, u16* __restrict__ oAh, u16* __restrict__ oAl,
                       const float* __restrict__ inB, u16* __restrict__ oBh, u16* __restrict__ oBl)
{
    __shared__ float t[32][33];
    int z = blockIdx.z;
    const float* in; u16* oh; u16* ol;
    if (z < E_) { in = inA; oh = oAh; ol = oAl; }
    else        { z -= E_; in = inB; oh = oBh; ol = oBl; }
    const int R = 512, C = 512;
    const float* ib = in + (size_t)z * R * C;
    u16* ohz = oh + (size_t)z * R * C;
    u16* olz = ol + (size_t)z * R * C;
    const int r0 = blockIdx.y * 32, c0 = blockIdx.x * 32;
    const int t8 = threadIdx.x & 7, td = threadIdx.x >> 3;

    float4 v = *(const float4*)&ib[(size_t)(r0 + td) * C + c0 + t8 * 4];
    t[td][t8 * 4 + 0] = v.x;
    t[td][t8 * 4 + 1] = v.y;
    t[td][t8 * 4 + 2] = v.z;
    t[td][t8 * 4 + 3] = v.w;
    __syncthreads();

    u16x4 ph, pl;
    float w0 = t[t8 * 4 + 0][td], w1 = t[t8 * 4 + 1][td];
    float w2 = t[t8 * 4 + 2][td], w3 = t[t8 * 4 + 3][td];
    ph.x = f2bf(w0); pl.x = f2bf(w0 - bf2f(ph.x));
    ph.y = f2bf(w1); pl.y = f2bf(w1 - bf2f(ph.y));
    ph.z = f2bf(w2); pl.z = f2bf(w2 - bf2f(ph.z));
    ph.w = f2bf(w3); pl.w = f2bf(w3 - bf2f(ph.w));
    const size_t o = (size_t)(c0 + td) * R + r0 + t8 * 4;
    *(u16x4*)&ohz[o] = ph;
    *(u16x4*)&olz[o] = pl;
}

// ---------------------------------------------------------------------------
// Split-bf16 GEMM (3 MFMA: hh + hl + lh): C[z][m][n] = sum_k A[m][k]*B[n][k]
// 128x128 tile, 256 threads (4 waves), BK=32, 16x16x32 bf16 MFMA.
// Rotated fragment-order LDS (see header comment). 16 grps per operand (hi/lo
// interleaved at grp bit 0): grp = half*8 + i*2 + lo.
// sym=1: A==B symmetric output. grid.x = 10 upper-tri blocks; off-diag blocks
// also write the transposed tile (vectorized u16x4: 4 consecutive rows/lane).
// ---------------------------------------------------------------------------
__global__ __launch_bounds__(256)
void gemm_split3(const u16* __restrict__ Ah, const u16* __restrict__ Al,
                 int aMod, long aStride,
                 const u16* __restrict__ Bh, const u16* __restrict__ Bl,
                 int bMod, long bStride,
                 u16* __restrict__ Ch, u16* __restrict__ Cl,
                 float* __restrict__ Cf,
                 int M, int N, int K, int f32out, int sym)
{
    const int z = blockIdx.z;
    const long za = aMod ? (z % aMod) : z;
    const long zb = bMod ? (z % bMod) : z;
    const u16* pAh = Ah + za * aStride;
    const u16* pAl = Al + za * aStride;
    const u16* pBh = Bh + zb * bStride;
    const u16* pBl = Bl + zb * bStride;

    __shared__ __attribute__((aligned(16))) u16 sA[8192];   // 16 KiB, 16 grps
    __shared__ __attribute__((aligned(16))) u16 sB[8192];

    const int tid = threadIdx.x;
    const int wv = tid >> 6, ln = tid & 63;
    const int lq = ln >> 4, lm = ln & 15;

    int bi, bj;
    if (sym) {
        const int idx = blockIdx.x;          // upper triangle of 4x4
        bi = (idx < 4) ? 0 : (idx < 7) ? 1 : (idx < 9) ? 2 : 3;
        bj = idx - ((bi == 0) ? 0 : (bi == 1) ? 3 : (bi == 2) ? 5 : 6);
    } else { bi = blockIdx.x; bj = blockIdx.y; }
    const int m0 = bi * 128, n0 = bj * 128;

    // staging: lane ln stages chunk ci=ln of grp; global (row rg, kq rotated)
    const int rg = ln >> 2;                       // row within 16-row grp
    const int kq = ((ln & 3) + (rg >> 1)) & 3;    // rotated k-quad
    const u16* srcA[4];
    const u16* srcB[4];
#pragma unroll
    for (int g = 0; g < 4; ++g) {
        const int grp = wv * 4 + g;
        const int row = (grp >> 3) * 64 + ((grp >> 1) & 3) * 16 + rg;
        srcA[g] = ((grp & 1) ? pAl : pAh) + (long)(m0 + row) * K + kq * 8;
        srcB[g] = ((grp & 1) ? pBl : pBh) + (long)(n0 + row) * K + kq * 8;
    }

    // fragment read: chunk co = 4*lm + ((lq - (lm>>1)) & 3), 8 u16 per chunk
    const int co = (lm * 4 + ((lq - (lm >> 1)) & 3)) * 8;

    const int wm = wv >> 1, wn = wv & 1;

    floatx4 acc[4][4];
#pragma unroll
    for (int i = 0; i < 4; ++i)
#pragma unroll
        for (int j = 0; j < 4; ++j) acc[i][j] = (floatx4){0.f, 0.f, 0.f, 0.f};

    for (int k0 = 0; k0 < K; k0 += 32) {
#pragma unroll
        for (int g = 0; g < 4; ++g) {
            GLDS(srcA[g] + k0, sA + (wv * 4 + g) * 512);
            GLDS(srcB[g] + k0, sB + (wv * 4 + g) * 512);
        }
        __syncthreads();

        bf16x8 ah[4], al[4], bh[4], bl[4];
#pragma unroll
        for (int i = 0; i < 4; ++i) {
            const int ga = (wm * 8 + i * 2) * 512 + co;
            ah[i] = *(const bf16x8*)&sA[ga];
            al[i] = *(const bf16x8*)&sA[ga + 512];
        }
#pragma unroll
        for (int j = 0; j < 4; ++j) {
            const int gb = (wn * 8 + j * 2) * 512 + co;
            bh[j] = *(const bf16x8*)&sB[gb];
            bl[j] = *(const bf16x8*)&sB[gb + 512];
        }
#pragma unroll
        for (int i = 0; i < 4; ++i)
#pragma unroll
            for (int j = 0; j < 4; ++j) {
                acc[i][j] = __builtin_amdgcn_mfma_f32_16x16x32_bf16(ah[i], bh[j], acc[i][j], 0, 0, 0);
                acc[i][j] = __builtin_amdgcn_mfma_f32_16x16x32_bf16(ah[i], bl[j], acc[i][j], 0, 0, 0);
                acc[i][j] = __builtin_amdgcn_mfma_f32_16x16x32_bf16(al[i], bh[j], acc[i][j], 0, 0, 0);
            }
        __syncthreads();
    }

    // epilogue: C/D layout col=lane&15, row=quad*4+reg
    const long cbase = (long)z * M * N;
#pragma unroll
    for (int i = 0; i < 4; ++i)
#pragma unroll
        for (int j = 0; j < 4; ++j) {
            const int col = n0 + wn * 64 + j * 16 + lm;
            const int row0 = m0 + wm * 64 + i * 16 + lq * 4;
            if (f32out) {
#pragma unroll
                for (int r = 0; r < 4; ++r)
                    Cf[cbase + (long)(row0 + r) * N + col] = acc[i][j][r];
            } else {
                u16x4 hv, lv;
#pragma unroll
                for (int r = 0; r < 4; ++r) {
                    const float v = acc[i][j][r];
                    const u16 h = f2bf(v);
                    hv[r] = h;
                    lv[r] = f2bf(v - bf2f(h));
                    Ch[cbase + (long)(row0 + r) * N + col] = h;
                    Cl[cbase + (long)(row0 + r) * N + col] = lv[r];
                }
                if (sym && bi != bj) {   // mirror tile: rows are 4-consecutive
                    const long mb = cbase + (long)col * N + row0;
                    *(u16x4*)&Ch[mb] = hv;
                    *(u16x4*)&Cl[mb] = lv;
                }
            }
        }
}

// ---------------------------------------------------------------------------
// Plain bf16 GEMM, one operand staged on-the-fly from fp32 (hi only).
// OTFA=1: A = Qf (fp32 otf), B = Pb (bf16). OTFA=0: A = Pb, B = Qf.
// Same rotated fragment-order layout. 8 grps per operand (8 KiB each).
// ---------------------------------------------------------------------------
template<int OTFA, int F32OUT>
__global__ __launch_bounds__(256)
void gemm_plain(const float* __restrict__ Qf, int qMod, long qStride,
                const u16* __restrict__ Pb, int pMod, long pStride,
                u16* __restrict__ Cb, float* __restrict__ Cf,
                int M, int N, int K)
{
    const int z = blockIdx.z;
    const float* pQ = Qf + (long)(qMod ? z % qMod : z) * qStride;
    const u16*  pP = Pb + (long)(pMod ? z % pMod : z) * pStride;

    __shared__ __attribute__((aligned(16))) u16 sA[4096];   // 8 KiB, 8 grps
    __shared__ __attribute__((aligned(16))) u16 sB[4096];

    const int tid = threadIdx.x;
    const int wv = tid >> 6, ln = tid & 63;
    const int lq = ln >> 4, lm = ln & 15;
    const int m0 = blockIdx.x * 128, n0 = blockIdx.y * 128;

    u16* sBF = OTFA ? sB : sA;   // bf16-side (GLDS) LDS tile
    u16* sQ  = OTFA ? sA : sB;   // otf-fp32-side LDS tile
    const int bfRow0 = OTFA ? n0 : m0;
    const int qRow0  = OTFA ? m0 : n0;

    // GLDS bf16 sources: 2 grps per wave; rotated k-quad
    const int rg = ln >> 2;
    const int kqr = ((ln & 3) + (rg >> 1)) & 3;
    const u16* srcP[2];
#pragma unroll
    for (int g = 0; g < 2; ++g) {
        const int grp = wv * 2 + g;
        const int row = (grp >> 2) * 64 + (grp & 3) * 16 + rg;
        srcP[g] = pP + (long)(bfRow0 + row) * K + kqr * 8;
    }

    // otf fp32: thread stages chunks {tid, tid+256}; same rotated mapping
    int orow[2], ok[2];
#pragma unroll
    for (int s = 0; s < 2; ++s) {
        const int ci = tid + s * 256;
        const int grp = ci >> 6, l = ci & 63;
        const int rr = l >> 2;
        orow[s] = qRow0 + (grp >> 2) * 64 + (grp & 3) * 16 + rr;
        ok[s]   = (((l & 3) + (rr >> 1)) & 3) * 8;
    }

    const int co = (lm * 4 + ((lq - (lm >> 1)) & 3)) * 8;

    const int wm = wv >> 1, wn = wv & 1;

    floatx4 acc[4][4];
#pragma unroll
    for (int i = 0; i < 4; ++i)
#pragma unroll
        for (int j = 0; j < 4; ++j) acc[i][j] = (floatx4){0.f, 0.f, 0.f, 0.f};

    for (int k0 = 0; k0 < K; k0 += 32) {
#pragma unroll
        for (int g = 0; g < 2; ++g)
            GLDS(srcP[g] + k0, sBF + (wv * 2 + g) * 512);
#pragma unroll
        for (int s = 0; s < 2; ++s) {
            const float* src = &pQ[(long)orow[s] * K + k0 + ok[s]];
            const float4 v0 = *(const float4*)src;
            const float4 v1 = *(const float4*)(src + 4);
            u16x8 pk;
            pk[0] = f2bf(v0.x); pk[1] = f2bf(v0.y); pk[2] = f2bf(v0.z); pk[3] = f2bf(v0.w);
            pk[4] = f2bf(v1.x); pk[5] = f2bf(v1.y); pk[6] = f2bf(v1.z); pk[7] = f2bf(v1.w);
            *(u16x8*)&sQ[(tid + s * 256) * 8] = pk;
        }
        __syncthreads();

        bf16x8 af[4], bg[4];
#pragma unroll
        for (int i = 0; i < 4; ++i)
            af[i] = *(const bf16x8*)&sA[(wm * 4 + i) * 512 + co];
#pragma unroll
        for (int j = 0; j < 4; ++j)
            bg[j] = *(const bf16x8*)&sB[(wn * 4 + j) * 512 + co];
#pragma unroll
        for (int i = 0; i < 4; ++i)
#pragma unroll
            for (int j = 0; j < 4; ++j)
                acc[i][j] = __builtin_amdgcn_mfma_f32_16x16x32_bf16(af[i], bg[j], acc[i][j], 0, 0, 0);
        __syncthreads();
    }

    const long cbase = (long)z * M * N;
#pragma unroll
    for (int i = 0; i < 4; ++i)
#pragma unroll
        for (int j = 0; j < 4; ++j) {
            const int col = n0 + wn * 64 + j * 16 + lm;
#pragma unroll
            for (int r = 0; r < 4; ++r) {
                const int row = m0 + wm * 64 + i * 16 + lq * 4 + r;
                const long idx = cbase + (long)row * N + col;
                if (F32OUT) Cf[idx] = acc[i][j][r];
                else        Cb[idx] = f2bf(acc[i][j][r]);
            }
        }
}

// ---------------------------------------------------------------------------
// Column softmax: AT fp32 [z][512][512], normalize over row index c per col g.
// ---------------------------------------------------------------------------
__global__ __launch_bounds__(128)
void softmax_col(const float* __restrict__ AT, u16* __restrict__ PT)
{
    const int z = blockIdx.x >> 2, gq = blockIdx.x & 3;
    const long base = (long)z * 512 * 512 + gq * 128 + threadIdx.x;
    const float* a = AT + base;
    u16* p = PT + base;

    float m = -1e30f, l = 0.f;
    for (int c = 0; c < 512; ++c) {
        const float v = a[(long)c * 512];
        const float mn = fmaxf(m, v);
        l = l * __expf(m - mn) + __expf(v - mn);
        m = mn;
    }
    const float inv = 1.0f / l;
    for (int c = 0; c < 512; ++c) {
        const float v = a[(long)c * 512];
        p[(long)c * 512] = f2bf(__expf(v - m) * inv);
    }
}

// ---------------------------------------------------------------------------
// Orchestration.  atten = softmax(W1^T (X^T X) W2), out = X (W3 atten).
// Buffer schedule (ws 64 MiB + d_out 128 MiB scratch):
//   C1: X -> XhT(O[0:64)), XlT(O[64:128))
//   S1: Gh(ws[0:32)), Gl(ws[32:64)) = XT*XT^T   (K=1024, SYMMETRIC: 10 blocks/z)
//   C2: w2 -> W2T h/l (O[64:80)), w1 -> W1T h/l (O[80:96))   [XlT dead]
//   S2: Uh(O[0:32)), Ul(O[32:64)) = W2T*G^T                  [XhT dead]
//   S3: AT fp32 (ws[0:64)) = U*W1T^T                         [G dead]
//   S4: PT bf16 (O[64:96)) = colsoftmax(AT)                  [W2T/W1T dead]
//   S5: MT bf16 (ws[0:32)) = PT*W3^T (W3 otf)                [AT dead]
//   S6: out fp32 (d_out) = X*MT^T (X otf)   [reads only x, MT]
// ---------------------------------------------------------------------------
extern "C" void kernel_launch(void* const* d_in, const int* in_sizes, int n_in,
                              void* d_out, int out_size, void* d_ws, size_t ws_size,
                              hipStream_t stream)
{
    const float* x  = (const float*)d_in[0];
    const float* w1 = (const float*)d_in[1];
    const float* w2 = (const float*)d_in[2];
    const float* w3 = (const float*)d_in[3];

    char* O = (char*)d_out;
    char* W = (char*)d_ws;
    const size_t MB = 1ull << 20;

    u16* XhT  = (u16*)O;
    u16* XlT  = (u16*)(O + 64 * MB);
    u16* Gh   = (u16*)W;
    u16* Gl   = (u16*)(W + 32 * MB);
    u16* W2Th = (u16*)(O + 64 * MB);
    u16* W2Tl = (u16*)(O + 72 * MB);
    u16* W1Th = (u16*)(O + 80 * MB);
    u16* W1Tl = (u16*)(O + 88 * MB);
    u16* Uh   = (u16*)O;
    u16* Ul   = (u16*)(O + 32 * MB);
    float* AT = (float*)W;
    u16* PT   = (u16*)(O + 64 * MB);
    u16* MT   = (u16*)W;
    float* out = (float*)d_out;

    const long sXT = (long)512 * 1024;
    const long sSq = (long)512 * 512;

    // C1: X [z][1024][512] -> XhT/XlT [z][512][1024]
    transpose_split<<<dim3(16, 32, BE), 256, 0, stream>>>(x, XhT, XlT, 1024, 512);
    // S1: G = XT * XT^T (split3, K=1024, symmetric: upper-tri + mirror)
    gemm_split3<<<dim3(10, 1, BE), 256, 0, stream>>>(
        XhT, XlT, 0, sXT, XhT, XlT, 0, sXT,
        Gh, Gl, nullptr, 512, 512, 1024, 0, 1);
    // C2: w2 -> W2T, w1 -> W1T (one dispatch)
    transpose_split_w<<<dim3(16, 16, 2 * E_), 256, 0, stream>>>(
        w2, W2Th, W2Tl, w1, W1Th, W1Tl);
    // S2: U = W2T * G^T  (G symmetric)
    gemm_split3<<<dim3(4, 4, BE), 256, 0, stream>>>(
        W2Th, W2Tl, E_, sSq, Gh, Gl, 0, sSq,
        Uh, Ul, nullptr, 512, 512, 512, 0, 0);
    // S3: AT = U * W1T^T  -> fp32 logits, transposed ([c][g])
    gemm_split3<<<dim3(4, 4, BE), 256, 0, stream>>>(
        Uh, Ul, 0, sSq, W1Th, W1Tl, E_, sSq,
        nullptr, nullptr, AT, 512, 512, 512, 1, 0);
    // S4: softmax over c (down the columns of AT)
    softmax_col<<<dim3(BE * 4), 128, 0, stream>>>(AT, PT);
    // S5: MT = PT * W3^T  (W3 fp32 on-the-fly as B)
    gemm_plain<0, 0><<<dim3(4, 4, BE), 256, 0, stream>>>(
        w3, E_, sSq, PT, 0, sSq, MT, nullptr, 512, 512, 512);
    // S6: out = X * MT^T  (X fp32 on-the-fly as A)
    gemm_plain<1, 1><<<dim3(8, 4, BE), 256, 0, stream>>>(
        x, 0, (long)N_ * D_, MT, 0, sSq, nullptr, out, 1024, 512, 512);
}

// Round 3
// 748.185 us; speedup vs baseline: 1.1240x; 1.0035x over previous
//
#include <hip/hip_runtime.h>
#include <stdint.h>

typedef unsigned short u16;
typedef __attribute__((ext_vector_type(8))) short bf16x8;
typedef __attribute__((ext_vector_type(4))) float floatx4;
typedef __attribute__((ext_vector_type(4))) u16 u16x4;
typedef __attribute__((ext_vector_type(8))) u16 u16x8;

constexpr int B_ = 4, E_ = 16, N_ = 1024, D_ = 512;
constexpr int BE = B_ * E_;

__device__ __forceinline__ u16 f2bf(float f) {
    union { float f; uint32_t u; } v; v.f = f;
    return (u16)((v.u + 0x7fffu + ((v.u >> 16) & 1u)) >> 16);
}
__device__ __forceinline__ float bf2f(u16 h) {
    union { uint32_t u; float f; } v; v.u = ((uint32_t)h) << 16;
    return v.f;
}

// async global->LDS, 16B per lane, LDS dest = wave-uniform base + lane*16
#define GLDS(g, l) __builtin_amdgcn_global_load_lds( \
    (const __attribute__((address_space(1))) void*)(g), \
    (__attribute__((address_space(3))) void*)(l), 16, 0, 0)

// ---------------------------------------------------------------------------
// K-quad rotation layout ("rotated fragment order"):
// A BK=32 panel of 16 rows is one LDS "grp" = 64 chunks x 16B = 1KB.
// Chunk ci (staged by lane ci): global row rg = ci>>2, k-quad kq = ((ci&3)+(rg>>1))&3.
//  - staging: 4 consecutive lanes cover ONE contiguous 64B row segment (VMEM
//    coalescing identical to plain row-major; only intra-line lane order rotated).
//  - fragment read: lane (lm,lq) reads chunk 4*lm + ((lq-(lm>>1))&3); the 16B-group
//    sequence (4t-(t>>1)) mod 8 is a permutation of 0..7 for every 8 consecutive
//    lanes -> conflict-free ds_read_b128.  [verified round 2: SQ_LDS_BANK_CONFLICT=0]
// ---------------------------------------------------------------------------

// ---------------------------------------------------------------------------
// Transpose + split-convert: in [z][R][C] fp32 -> outH/outL [z][C][R] bf16
// ---------------------------------------------------------------------------
__global__ __launch_bounds__(256)
void transpose_split(const float* __restrict__ in, u16* __restrict__ outH,
                     u16* __restrict__ outL, int R, int C)
{
    __shared__ float t[32][33];
    const int z = blockIdx.z;
    const float* ib = in + (size_t)z * R * C;
    u16* oh = outH + (size_t)z * R * C;
    u16* ol = outL + (size_t)z * R * C;
    const int r0 = blockIdx.y * 32, c0 = blockIdx.x * 32;
    const int t8 = threadIdx.x & 7, td = threadIdx.x >> 3;

    float4 v = *(const float4*)&ib[(size_t)(r0 + td) * C + c0 + t8 * 4];
    t[td][t8 * 4 + 0] = v.x;
    t[td][t8 * 4 + 1] = v.y;
    t[td][t8 * 4 + 2] = v.z;
    t[td][t8 * 4 + 3] = v.w;
    __syncthreads();

    u16x4 ph, pl;
    float w0 = t[t8 * 4 + 0][td], w1 = t[t8 * 4 + 1][td];
    float w2 = t[t8 * 4 + 2][td], w3 = t[t8 * 4 + 3][td];
    ph.x = f2bf(w0); pl.x = f2bf(w0 - bf2f(ph.x));
    ph.y = f2bf(w1); pl.y = f2bf(w1 - bf2f(ph.y));
    ph.z = f2bf(w2); pl.z = f2bf(w2 - bf2f(ph.z));
    ph.w = f2bf(w3); pl.w = f2bf(w3 - bf2f(ph.w));
    const size_t o = (size_t)(c0 + td) * R + r0 + t8 * 4;
    *(u16x4*)&oh[o] = ph;
    *(u16x4*)&ol[o] = pl;
}

// Both weight transposes (w2 and w1) in ONE dispatch. R=C=512, z in [0,2E)
__global__ __launch_bounds__(256)
void transpose_split_w(const float* __restrict__ inA, u16* __restrict__ oAh, u16* __restrict__ oAl,
                       const float* __restrict__ inB, u16* __restrict__ oBh, u16* __restrict__ oBl)
{
    __shared__ float t[32][33];
    int z = blockIdx.z;
    const float* in; u16* oh; u16* ol;
    if (z < E_) { in = inA; oh = oAh; ol = oAl; }
    else        { z -= E_; in = inB; oh = oBh; ol = oBl; }
    const int R = 512, C = 512;
    const float* ib = in + (size_t)z * R * C;
    u16* ohz = oh + (size_t)z * R * C;
    u16* olz = ol + (size_t)z * R * C;
    const int r0 = blockIdx.y * 32, c0 = blockIdx.x * 32;
    const int t8 = threadIdx.x & 7, td = threadIdx.x >> 3;

    float4 v = *(const float4*)&ib[(size_t)(r0 + td) * C + c0 + t8 * 4];
    t[td][t8 * 4 + 0] = v.x;
    t[td][t8 * 4 + 1] = v.y;
    t[td][t8 * 4 + 2] = v.z;
    t[td][t8 * 4 + 3] = v.w;
    __syncthreads();

    u16x4 ph, pl;
    float w0 = t[t8 * 4 + 0][td], w1 = t[t8 * 4 + 1][td];
    float w2 = t[t8 * 4 + 2][td], w3 = t[t8 * 4 + 3][td];
    ph.x = f2bf(w0); pl.x = f2bf(w0 - bf2f(ph.x));
    ph.y = f2bf(w1); pl.y = f2bf(w1 - bf2f(ph.y));
    ph.z = f2bf(w2); pl.z = f2bf(w2 - bf2f(ph.z));
    ph.w = f2bf(w3); pl.w = f2bf(w3 - bf2f(ph.w));
    const size_t o = (size_t)(c0 + td) * R + r0 + t8 * 4;
    *(u16x4*)&ohz[o] = ph;
    *(u16x4*)&olz[o] = pl;
}

// Plain fp32 -> bf16 (round-to-nearest-even) grid-stride cast, float4-wide.
__global__ __launch_bounds__(256)
void cast_bf16(const float* __restrict__ in, u16* __restrict__ out, long n4)
{
    const long stride = (long)gridDim.x * blockDim.x;
    for (long i = (long)blockIdx.x * blockDim.x + threadIdx.x; i < n4; i += stride) {
        const float4 v = *(const float4*)&in[i * 4];
        u16x4 p;
        p.x = f2bf(v.x); p.y = f2bf(v.y); p.z = f2bf(v.z); p.w = f2bf(v.w);
        *(u16x4*)&out[i * 4] = p;
    }
}

// ---------------------------------------------------------------------------
// Split-bf16 GEMM (3 MFMA: hh + hl + lh): C[z][m][n] = sum_k A[m][k]*B[n][k]
// 128x128 tile, 256 threads (4 waves), BK=32, 16x16x32 bf16 MFMA.
// Rotated fragment-order LDS (see header comment). 16 grps per operand (hi/lo
// interleaved at grp bit 0): grp = half*8 + i*2 + lo.
// NOTE: grid must be (M/128, N/128, z) -- full rectangular; symmetric-triangle
// decomposition regressed (640 blocks -> 2.5/CU -> MfmaUtil 19%, round 2).
// ---------------------------------------------------------------------------
__global__ __launch_bounds__(256)
void gemm_split3(const u16* __restrict__ Ah, const u16* __restrict__ Al,
                 int aMod, long aStride,
                 const u16* __restrict__ Bh, const u16* __restrict__ Bl,
                 int bMod, long bStride,
                 u16* __restrict__ Ch, u16* __restrict__ Cl,
                 float* __restrict__ Cf,
                 int M, int N, int K, int f32out)
{
    const int z = blockIdx.z;
    const long za = aMod ? (z % aMod) : z;
    const long zb = bMod ? (z % bMod) : z;
    const u16* pAh = Ah + za * aStride;
    const u16* pAl = Al + za * aStride;
    const u16* pBh = Bh + zb * bStride;
    const u16* pBl = Bl + zb * bStride;

    __shared__ __attribute__((aligned(16))) u16 sA[8192];   // 16 KiB, 16 grps
    __shared__ __attribute__((aligned(16))) u16 sB[8192];

    const int tid = threadIdx.x;
    const int wv = tid >> 6, ln = tid & 63;
    const int lq = ln >> 4, lm = ln & 15;
    const int m0 = blockIdx.x * 128, n0 = blockIdx.y * 128;

    // staging: lane ln stages chunk ci=ln of grp; global (row rg, kq rotated)
    const int rg = ln >> 2;                       // row within 16-row grp
    const int kq = ((ln & 3) + (rg >> 1)) & 3;    // rotated k-quad
    const u16* srcA[4];
    const u16* srcB[4];
#pragma unroll
    for (int g = 0; g < 4; ++g) {
        const int grp = wv * 4 + g;
        const int row = (grp >> 3) * 64 + ((grp >> 1) & 3) * 16 + rg;
        srcA[g] = ((grp & 1) ? pAl : pAh) + (long)(m0 + row) * K + kq * 8;
        srcB[g] = ((grp & 1) ? pBl : pBh) + (long)(n0 + row) * K + kq * 8;
    }

    // fragment read: chunk co = 4*lm + ((lq - (lm>>1)) & 3), 8 u16 per chunk
    const int co = (lm * 4 + ((lq - (lm >> 1)) & 3)) * 8;

    const int wm = wv >> 1, wn = wv & 1;

    floatx4 acc[4][4];
#pragma unroll
    for (int i = 0; i < 4; ++i)
#pragma unroll
        for (int j = 0; j < 4; ++j) acc[i][j] = (floatx4){0.f, 0.f, 0.f, 0.f};

    for (int k0 = 0; k0 < K; k0 += 32) {
#pragma unroll
        for (int g = 0; g < 4; ++g) {
            GLDS(srcA[g] + k0, sA + (wv * 4 + g) * 512);
            GLDS(srcB[g] + k0, sB + (wv * 4 + g) * 512);
        }
        __syncthreads();

        bf16x8 ah[4], al[4], bh[4], bl[4];
#pragma unroll
        for (int i = 0; i < 4; ++i) {
            const int ga = (wm * 8 + i * 2) * 512 + co;
            ah[i] = *(const bf16x8*)&sA[ga];
            al[i] = *(const bf16x8*)&sA[ga + 512];
        }
#pragma unroll
        for (int j = 0; j < 4; ++j) {
            const int gb = (wn * 8 + j * 2) * 512 + co;
            bh[j] = *(const bf16x8*)&sB[gb];
            bl[j] = *(const bf16x8*)&sB[gb + 512];
        }
#pragma unroll
        for (int i = 0; i < 4; ++i)
#pragma unroll
            for (int j = 0; j < 4; ++j) {
                acc[i][j] = __builtin_amdgcn_mfma_f32_16x16x32_bf16(ah[i], bh[j], acc[i][j], 0, 0, 0);
                acc[i][j] = __builtin_amdgcn_mfma_f32_16x16x32_bf16(ah[i], bl[j], acc[i][j], 0, 0, 0);
                acc[i][j] = __builtin_amdgcn_mfma_f32_16x16x32_bf16(al[i], bh[j], acc[i][j], 0, 0, 0);
            }
        __syncthreads();
    }

    // epilogue: C/D layout col=lane&15, row=quad*4+reg
    const long cbase = (long)z * M * N;
#pragma unroll
    for (int i = 0; i < 4; ++i)
#pragma unroll
        for (int j = 0; j < 4; ++j) {
            const int col = n0 + wn * 64 + j * 16 + lm;
            const int row0 = m0 + wm * 64 + i * 16 + lq * 4;
#pragma unroll
            for (int r = 0; r < 4; ++r) {
                const float v = acc[i][j][r];
                const long idx = cbase + (long)(row0 + r) * N + col;
                if (f32out) {
                    Cf[idx] = v;
                } else {
                    const u16 h = f2bf(v);
                    Ch[idx] = h;
                    Cl[idx] = f2bf(v - bf2f(h));
                }
            }
        }
}

// ---------------------------------------------------------------------------
// Plain bf16 GEMM, BOTH operands bf16 via GLDS (rotated layout, 8 grps each).
// C[z][m][n] = sum_k A[m][k]*B[n][k].
// ---------------------------------------------------------------------------
template<int F32OUT>
__global__ __launch_bounds__(256)
void gemm_bb(const u16* __restrict__ Ab, int aMod, long aStride,
             const u16* __restrict__ Bb, int bMod, long bStride,
             u16* __restrict__ Cb, float* __restrict__ Cf,
             int M, int N, int K)
{
    const int z = blockIdx.z;
    const u16* pA = Ab + (long)(aMod ? z % aMod : z) * aStride;
    const u16* pB = Bb + (long)(bMod ? z % bMod : z) * bStride;

    __shared__ __attribute__((aligned(16))) u16 sA[4096];   // 8 KiB, 8 grps
    __shared__ __attribute__((aligned(16))) u16 sB[4096];

    const int tid = threadIdx.x;
    const int wv = tid >> 6, ln = tid & 63;
    const int lq = ln >> 4, lm = ln & 15;
    const int m0 = blockIdx.x * 128, n0 = blockIdx.y * 128;

    const int rg = ln >> 2;
    const int kq = ((ln & 3) + (rg >> 1)) & 3;
    const u16* srcA[2];
    const u16* srcB[2];
#pragma unroll
    for (int g = 0; g < 2; ++g) {
        const int grp = wv * 2 + g;
        const int row = (grp >> 2) * 64 + (grp & 3) * 16 + rg;
        srcA[g] = pA + (long)(m0 + row) * K + kq * 8;
        srcB[g] = pB + (long)(n0 + row) * K + kq * 8;
    }

    const int co = (lm * 4 + ((lq - (lm >> 1)) & 3)) * 8;
    const int wm = wv >> 1, wn = wv & 1;

    floatx4 acc[4][4];
#pragma unroll
    for (int i = 0; i < 4; ++i)
#pragma unroll
        for (int j = 0; j < 4; ++j) acc[i][j] = (floatx4){0.f, 0.f, 0.f, 0.f};

    for (int k0 = 0; k0 < K; k0 += 32) {
#pragma unroll
        for (int g = 0; g < 2; ++g) {
            GLDS(srcA[g] + k0, sA + (wv * 2 + g) * 512);
            GLDS(srcB[g] + k0, sB + (wv * 2 + g) * 512);
        }
        __syncthreads();

        bf16x8 af[4], bg[4];
#pragma unroll
        for (int i = 0; i < 4; ++i)
            af[i] = *(const bf16x8*)&sA[(wm * 4 + i) * 512 + co];
#pragma unroll
        for (int j = 0; j < 4; ++j)
            bg[j] = *(const bf16x8*)&sB[(wn * 4 + j) * 512 + co];
#pragma unroll
        for (int i = 0; i < 4; ++i)
#pragma unroll
            for (int j = 0; j < 4; ++j)
                acc[i][j] = __builtin_amdgcn_mfma_f32_16x16x32_bf16(af[i], bg[j], acc[i][j], 0, 0, 0);
        __syncthreads();
    }

    const long cbase = (long)z * M * N;
#pragma unroll
    for (int i = 0; i < 4; ++i)
#pragma unroll
        for (int j = 0; j < 4; ++j) {
            const int col = n0 + wn * 64 + j * 16 + lm;
#pragma unroll
            for (int r = 0; r < 4; ++r) {
                const int row = m0 + wm * 64 + i * 16 + lq * 4 + r;
                const long idx = cbase + (long)row * N + col;
                if (F32OUT) Cf[idx] = acc[i][j][r];
                else        Cb[idx] = f2bf(acc[i][j][r]);
            }
        }
}

// ---------------------------------------------------------------------------
// Plain bf16 GEMM, one operand staged on-the-fly from fp32 (hi only).
// OTFA=1: A = Qf (fp32 otf), B = Pb (bf16). OTFA=0: A = Pb, B = Qf.
// ---------------------------------------------------------------------------
template<int OTFA, int F32OUT>
__global__ __launch_bounds__(256)
void gemm_plain(const float* __restrict__ Qf, int qMod, long qStride,
                const u16* __restrict__ Pb, int pMod, long pStride,
                u16* __restrict__ Cb, float* __restrict__ Cf,
                int M, int N, int K)
{
    const int z = blockIdx.z;
    const float* pQ = Qf + (long)(qMod ? z % qMod : z) * qStride;
    const u16*  pP = Pb + (long)(pMod ? z % pMod : z) * pStride;

    __shared__ __attribute__((aligned(16))) u16 sA[4096];   // 8 KiB, 8 grps
    __shared__ __attribute__((aligned(16))) u16 sB[4096];

    const int tid = threadIdx.x;
    const int wv = tid >> 6, ln = tid & 63;
    const int lq = ln >> 4, lm = ln & 15;
    const int m0 = blockIdx.x * 128, n0 = blockIdx.y * 128;

    u16* sBF = OTFA ? sB : sA;   // bf16-side (GLDS) LDS tile
    u16* sQ  = OTFA ? sA : sB;   // otf-fp32-side LDS tile
    const int bfRow0 = OTFA ? n0 : m0;
    const int qRow0  = OTFA ? m0 : n0;

    // GLDS bf16 sources: 2 grps per wave; rotated k-quad
    const int rg = ln >> 2;
    const int kqr = ((ln & 3) + (rg >> 1)) & 3;
    const u16* srcP[2];
#pragma unroll
    for (int g = 0; g < 2; ++g) {
        const int grp = wv * 2 + g;
        const int row = (grp >> 2) * 64 + (grp & 3) * 16 + rg;
        srcP[g] = pP + (long)(bfRow0 + row) * K + kqr * 8;
    }

    // otf fp32: thread stages chunks {tid, tid+256}; same rotated mapping
    int orow[2], ok[2];
#pragma unroll
    for (int s = 0; s < 2; ++s) {
        const int ci = tid + s * 256;
        const int grp = ci >> 6, l = ci & 63;
        const int rr = l >> 2;
        orow[s] = qRow0 + (grp >> 2) * 64 + (grp & 3) * 16 + rr;
        ok[s]   = (((l & 3) + (rr >> 1)) & 3) * 8;
    }

    const int co = (lm * 4 + ((lq - (lm >> 1)) & 3)) * 8;

    const int wm = wv >> 1, wn = wv & 1;

    floatx4 acc[4][4];
#pragma unroll
    for (int i = 0; i < 4; ++i)
#pragma unroll
        for (int j = 0; j < 4; ++j) acc[i][j] = (floatx4){0.f, 0.f, 0.f, 0.f};

    for (int k0 = 0; k0 < K; k0 += 32) {
#pragma unroll
        for (int g = 0; g < 2; ++g)
            GLDS(srcP[g] + k0, sBF + (wv * 2 + g) * 512);
#pragma unroll
        for (int s = 0; s < 2; ++s) {
            const float* src = &pQ[(long)orow[s] * K + k0 + ok[s]];
            const float4 v0 = *(const float4*)src;
            const float4 v1 = *(const float4*)(src + 4);
            u16x8 pk;
            pk[0] = f2bf(v0.x); pk[1] = f2bf(v0.y); pk[2] = f2bf(v0.z); pk[3] = f2bf(v0.w);
            pk[4] = f2bf(v1.x); pk[5] = f2bf(v1.y); pk[6] = f2bf(v1.z); pk[7] = f2bf(v1.w);
            *(u16x8*)&sQ[(tid + s * 256) * 8] = pk;
        }
        __syncthreads();

        bf16x8 af[4], bg[4];
#pragma unroll
        for (int i = 0; i < 4; ++i)
            af[i] = *(const bf16x8*)&sA[(wm * 4 + i) * 512 + co];
#pragma unroll
        for (int j = 0; j < 4; ++j)
            bg[j] = *(const bf16x8*)&sB[(wn * 4 + j) * 512 + co];
#pragma unroll
        for (int i = 0; i < 4; ++i)
#pragma unroll
            for (int j = 0; j < 4; ++j)
                acc[i][j] = __builtin_amdgcn_mfma_f32_16x16x32_bf16(af[i], bg[j], acc[i][j], 0, 0, 0);
        __syncthreads();
    }

    const long cbase = (long)z * M * N;
#pragma unroll
    for (int i = 0; i < 4; ++i)
#pragma unroll
        for (int j = 0; j < 4; ++j) {
            const int col = n0 + wn * 64 + j * 16 + lm;
#pragma unroll
            for (int r = 0; r < 4; ++r) {
                const int row = m0 + wm * 64 + i * 16 + lq * 4 + r;
                const long idx = cbase + (long)row * N + col;
                if (F32OUT) Cf[idx] = acc[i][j][r];
                else        Cb[idx] = f2bf(acc[i][j][r]);
            }
        }
}

// ---------------------------------------------------------------------------
// Column softmax: AT fp32 [z][512][512], normalize over row index c per col g.
// ---------------------------------------------------------------------------
__global__ __launch_bounds__(128)
void softmax_col(const float* __restrict__ AT, u16* __restrict__ PT)
{
    const int z = blockIdx.x >> 2, gq = blockIdx.x & 3;
    const long base = (long)z * 512 * 512 + gq * 128 + threadIdx.x;
    const float* a = AT + base;
    u16* p = PT + base;

    float m = -1e30f, l = 0.f;
    for (int c = 0; c < 512; ++c) {
        const float v = a[(long)c * 512];
        const float mn = fmaxf(m, v);
        l = l * __expf(m - mn) + __expf(v - mn);
        m = mn;
    }
    const float inv = 1.0f / l;
    for (int c = 0; c < 512; ++c) {
        const float v = a[(long)c * 512];
        p[(long)c * 512] = f2bf(__expf(v - m) * inv);
    }
}

// ---------------------------------------------------------------------------
// Orchestration.  atten = softmax(W1^T (X^T X) W2), out = X (W3 atten).
// Buffer schedule (ws >= 64 MiB + d_out 128 MiB scratch):
//   C1: X -> XhT(O[0:64)), XlT(O[64:128))
//   S1: Gh(ws[0:32)), Gl(ws[32:64)) = XT*XT^T   (K=1024, full 16 blocks/z)
//   C2: w2 -> W2T h/l (O[64:80)), w1 -> W1T h/l (O[80:96))   [XlT dead]
//   C3: w3 -> W3b bf16 (O[96:104))
//   S2: Uh(O[0:32)), Ul(O[32:64)) = W2T*G^T                  [XhT dead]
//   S3: AT fp32 (ws[0:64)) = U*W1T^T                         [G dead]
//   S4: PT bf16 (O[64:96)) = colsoftmax(AT)                  [W2T/W1T dead]
//   S5: MT bf16 (ws[0:32)) = PT*W3b^T  (pure bf16)           [AT dead]
//   S6: out fp32 (d_out) = X*MT^T (X otf)   [reads only x, MT]
// ---------------------------------------------------------------------------
extern "C" void kernel_launch(void* const* d_in, const int* in_sizes, int n_in,
                              void* d_out, int out_size, void* d_ws, size_t ws_size,
                              hipStream_t stream)
{
    const float* x  = (const float*)d_in[0];
    const float* w1 = (const float*)d_in[1];
    const float* w2 = (const float*)d_in[2];
    const float* w3 = (const float*)d_in[3];

    char* O = (char*)d_out;
    char* W = (char*)d_ws;
    const size_t MB = 1ull << 20;

    u16* XhT  = (u16*)O;
    u16* XlT  = (u16*)(O + 64 * MB);
    u16* Gh   = (u16*)W;
    u16* Gl   = (u16*)(W + 32 * MB);
    u16* W2Th = (u16*)(O + 64 * MB);
    u16* W2Tl = (u16*)(O + 72 * MB);
    u16* W1Th = (u16*)(O + 80 * MB);
    u16* W1Tl = (u16*)(O + 88 * MB);
    u16* W3b  = (u16*)(O + 96 * MB);
    u16* Uh   = (u16*)O;
    u16* Ul   = (u16*)(O + 32 * MB);
    float* AT = (float*)W;
    u16* PT   = (u16*)(O + 64 * MB);
    u16* MT   = (u16*)W;
    float* out = (float*)d_out;

    const long sXT = (long)512 * 1024;
    const long sSq = (long)512 * 512;

    // C1: X [z][1024][512] -> XhT/XlT [z][512][1024]
    transpose_split<<<dim3(16, 32, BE), 256, 0, stream>>>(x, XhT, XlT, 1024, 512);
    // S1: G = XT * XT^T (split3, K=1024, full rectangular grid)
    gemm_split3<<<dim3(4, 4, BE), 256, 0, stream>>>(
        XhT, XlT, 0, sXT, XhT, XlT, 0, sXT,
        Gh, Gl, nullptr, 512, 512, 1024, 0);
    // C2: w2 -> W2T, w1 -> W1T (one dispatch)
    transpose_split_w<<<dim3(16, 16, 2 * E_), 256, 0, stream>>>(
        w2, W2Th, W2Tl, w1, W1Th, W1Tl);
    // C3: w3 -> bf16 (bit-identical to previous on-the-fly f2bf)
    cast_bf16<<<dim3(1024), 256, 0, stream>>>(w3, W3b, (long)E_ * 512 * 512 / 4);
    // S2: U = W2T * G^T  (G symmetric)
    gemm_split3<<<dim3(4, 4, BE), 256, 0, stream>>>(
        W2Th, W2Tl, E_, sSq, Gh, Gl, 0, sSq,
        Uh, Ul, nullptr, 512, 512, 512, 0);
    // S3: AT = U * W1T^T  -> fp32 logits, transposed ([c][g])
    gemm_split3<<<dim3(4, 4, BE), 256, 0, stream>>>(
        Uh, Ul, 0, sSq, W1Th, W1Tl, E_, sSq,
        nullptr, nullptr, AT, 512, 512, 512, 1);
    // S4: softmax over c (down the columns of AT)
    softmax_col<<<dim3(BE * 4), 128, 0, stream>>>(AT, PT);
    // S5: MT = PT * W3b^T  (pure bf16 both sides)
    gemm_bb<0><<<dim3(4, 4, BE), 256, 0, stream>>>(
        PT, 0, sSq, W3b, E_, sSq, MT, nullptr, 512, 512, 512);
    // S6: out = X * MT^T  (X fp32 on-the-fly as A)
    gemm_plain<1, 1><<<dim3(8, 4, BE), 256, 0, stream>>>(
        x, 0, (long)N_ * D_, MT, 0, sSq, nullptr, out, 1024, 512, 512);
}